// Round 5
// baseline (204.077 us; speedup 1.0000x reference)
//
#include <hip/hip_runtime.h>

// Round 5: (1) deint_x: x -> 9 contiguous bf16 planes Xp[c][4096][512];
// (2) conv_w: W -> bf16 transposed Wt[ch][n][k];
// (3) gemm_d1: plane-0 GEMM, m97-style 128x128, direct coalesced stores + bias;
// (4) gemm_d35<D>: one block = 64 rows x 64 cols x ALL D irreps (wave i = plane i),
//     global_load_lds staging, epilogue routes C through LDS -> contiguous
//     64*D-float interleaved output rows. No Y round trip, no strided access.

#define BATCH 4096
#define DTOT 4608
#define NMUL 512

typedef __attribute__((ext_vector_type(8))) short short8;
typedef __attribute__((ext_vector_type(8))) unsigned short ushort8;
typedef __attribute__((ext_vector_type(4))) float float4v;

#define XPL_BYTES (9ull * BATCH * NMUL * 2)   // 37,748,736

__device__ __forceinline__ unsigned short f2bf(float f) {
    unsigned int u = __builtin_bit_cast(unsigned int, f);
    return (unsigned short)((u + 0x7fffu + ((u >> 16) & 1u)) >> 16);
}
__device__ __forceinline__ void gld16(const unsigned short* g, unsigned short* l) {
    __builtin_amdgcn_global_load_lds(
        (const __attribute__((address_space(1))) unsigned int*)(const void*)g,
        (__attribute__((address_space(3))) unsigned int*)(void*)l, 16, 0, 0);
}
__device__ __forceinline__ void colmap(int col, int& c, int& u) {
    if (col < 512)       { c = 0; u = col; }
    else if (col < 2048) { int t = col - 512;  c = 1 + t % 3; u = t / 3; }
    else                 { int t = col - 2048; c = 4 + t % 5; u = t / 5; }
}

// ---- phase 1: x[4096][4608] fp32 -> Xp[9][4096][512] bf16 ----
__global__ __launch_bounds__(256) void deint_x(const float* __restrict__ x,
                                               unsigned short* __restrict__ Xp) {
    const int row = blockIdx.x;
    __shared__ unsigned short buf[DTOT];
    const int tid = threadIdx.x;
    const float4v* src = (const float4v*)(x + (size_t)row * DTOT);
    for (int p = tid; p < DTOT / 4; p += 256) {
        float4v v = src[p];
#pragma unroll
        for (int j = 0; j < 4; ++j) {
            int c, u; colmap(p * 4 + j, c, u);
            buf[c * NMUL + u] = f2bf(v[j]);
        }
    }
    __syncthreads();
    for (int q = tid; q < DTOT / 8; q += 256) {
        const int c = q >> 6, u8 = q & 63;
        *(ushort8*)(Xp + ((size_t)(c * BATCH + row) * NMUL) + u8 * 8) =
            *(const ushort8*)&buf[c * NMUL + u8 * 8];
    }
}

// ---- phase 2: W[k][n] fp32 -> Wt[ch][n][k] bf16 ----
__global__ __launch_bounds__(256) void conv_w(const float* __restrict__ w0,
                                              const float* __restrict__ w1,
                                              const float* __restrict__ w2,
                                              unsigned short* __restrict__ Wt) {
    const int b = blockIdx.x;                 // 192 = 3 ch x 64 tiles
    const int ch = b >> 6, t = b & 63;
    const int tk = (t >> 3) * 64, tn = (t & 7) * 64;
    const float* W = (ch == 0) ? w0 : (ch == 1) ? w1 : w2;
    __shared__ unsigned short tile[64][72];
    const int tid = threadIdx.x;
    const int r0 = tid >> 4, c4 = (tid & 15) * 4;
#pragma unroll
    for (int rr = 0; rr < 4; ++rr) {
        const int row = r0 + rr * 16;
        float4v v = *(const float4v*)(W + (size_t)(tk + row) * NMUL + tn + c4);
#pragma unroll
        for (int j = 0; j < 4; ++j) tile[c4 + j][row] = f2bf(v[j]);
    }
    __syncthreads();
    for (int q = tid; q < 512; q += 256) {
        const int nn = q >> 3, k8 = q & 7;
        *(ushort8*)(Wt + ((size_t)(ch * NMUL + tn + nn) * NMUL) + tk + k8 * 8) =
            *(const ushort8*)&tile[nn][k8 * 8];
    }
}

// ---- phase 3a: d=1 GEMM (plane 0), direct coalesced stores + bias ----
__global__ __launch_bounds__(256) void gemm_d1(const unsigned short* __restrict__ Xp,
                                               const unsigned short* __restrict__ Wt,
                                               const float* __restrict__ b0,
                                               float* __restrict__ out) {
    const int n0 = blockIdx.x * 128;
    const int m0 = blockIdx.y * 128;
    __shared__ unsigned short As[128 * 32];
    __shared__ unsigned short Bs[128 * 32];

    const int tid = threadIdx.x;
    const int lane = tid & 63;
    const int w = tid >> 6;
    const int lr = lane & 15;
    const int lq = lane >> 4;
    const int wm = (w >> 1) * 64;
    const int wn = (w & 1) * 64;

    const unsigned short* Ag = Xp + (size_t)(m0 + w * 32 + (lane >> 2)) * NMUL + (lane & 3) * 8;
    const unsigned short* Bg = Wt + (size_t)(n0 + w * 32 + (lane >> 2)) * NMUL + (lane & 3) * 8;
    unsigned short* Al = As + w * 1024;
    unsigned short* Bl = Bs + w * 1024;

    float4v acc[4][4];
#pragma unroll
    for (int a = 0; a < 4; ++a)
#pragma unroll
        for (int b = 0; b < 4; ++b) acc[a][b] = (float4v)0.f;

    for (int kt = 0; kt < 16; ++kt) {
        const int ko = kt * 32;
        gld16(Ag + ko, Al);
        gld16(Ag + ko + 16 * NMUL, Al + 512);
        gld16(Bg + ko, Bl);
        gld16(Bg + ko + 16 * NMUL, Bl + 512);
        __syncthreads();
        short8 af[4], bf[4];
#pragma unroll
        for (int mi = 0; mi < 4; ++mi)
            af[mi] = *(const short8*)(As + (wm + mi * 16 + lr) * 32 + lq * 8);
#pragma unroll
        for (int ni = 0; ni < 4; ++ni)
            bf[ni] = *(const short8*)(Bs + (wn + ni * 16 + lr) * 32 + lq * 8);
#pragma unroll
        for (int mi = 0; mi < 4; ++mi)
#pragma unroll
            for (int ni = 0; ni < 4; ++ni)
                acc[mi][ni] = __builtin_amdgcn_mfma_f32_16x16x32_bf16(
                    af[mi], bf[ni], acc[mi][ni], 0, 0, 0);
        __syncthreads();
    }

    const float PW = 0.044194173824159216f;
#pragma unroll
    for (int ni = 0; ni < 4; ++ni) {
        const int col = n0 + wn + ni * 16 + lr;
        const float bias = b0[col];
#pragma unroll
        for (int mi = 0; mi < 4; ++mi)
#pragma unroll
            for (int r = 0; r < 4; ++r)
                out[(size_t)(m0 + wm + mi * 16 + lq * 4 + r) * DTOT + col] =
                    acc[mi][ni][r] * PW + bias;
    }
}

// ---- phase 3b: d in {3,5}: block = 64 rows x 64 cols x D irreps ----
template <int D, int PBASE, int XOFF, int WCH>
__global__ __launch_bounds__(D * 64) void gemm_d35(
    const unsigned short* __restrict__ Xp,
    const unsigned short* __restrict__ Wt,
    float* __restrict__ out)
{
    __shared__ unsigned short As[D * 2048];   // D planes x [64][32]
    __shared__ unsigned short Bs[2048];       // [64][32]
    float* Cs = (float*)As;                   // epilogue union (16 x 64*D floats)

    const int tid = threadIdx.x;
    const int lane = tid & 63;
    const int w = tid >> 6;                   // wave = irrep plane 0..D-1
    const int lr = lane & 15;
    const int lq = lane >> 4;

    const int n0 = blockIdx.x * 64;
    const int m0 = blockIdx.y * 64;

    const unsigned short* Ag =
        Xp + ((size_t)(PBASE + w) * BATCH + m0 + (lane >> 2)) * NMUL + (lane & 3) * 8;
    const unsigned short* Bg =
        Wt + ((size_t)WCH * NMUL + n0 + (lane >> 2)) * NMUL + (lane & 3) * 8;
    unsigned short* Al = As + w * 2048;

    float4v acc[4][4];
#pragma unroll
    for (int a = 0; a < 4; ++a)
#pragma unroll
        for (int b = 0; b < 4; ++b) acc[a][b] = (float4v)0.f;

    for (int kt = 0; kt < 16; ++kt) {
        const int ko = kt * 32;
#pragma unroll
        for (int p = 0; p < 4; ++p)           // wave stages its own plane: 4x16 rows
            gld16(Ag + (size_t)p * 16 * NMUL + ko, Al + p * 512);
        for (int p = w; p < 4; p += D)        // B tile split across waves
            gld16(Bg + (size_t)p * 16 * NMUL + ko, Bs + p * 512);
        __syncthreads();
        short8 af[4], bf[4];
#pragma unroll
        for (int mi = 0; mi < 4; ++mi)
            af[mi] = *(const short8*)(Al + (mi * 16 + lr) * 32 + lq * 8);
#pragma unroll
        for (int ni = 0; ni < 4; ++ni)
            bf[ni] = *(const short8*)(Bs + (ni * 16 + lr) * 32 + lq * 8);
#pragma unroll
        for (int mi = 0; mi < 4; ++mi)
#pragma unroll
            for (int ni = 0; ni < 4; ++ni)
                acc[mi][ni] = __builtin_amdgcn_mfma_f32_16x16x32_bf16(
                    af[mi], bf[ni], acc[mi][ni], 0, 0, 0);
        __syncthreads();
    }

    const float PW = 0.044194173824159216f;
#pragma unroll
    for (int mc = 0; mc < 4; ++mc) {          // 16-row chunks
#pragma unroll
        for (int ni = 0; ni < 4; ++ni)
#pragma unroll
            for (int r = 0; r < 4; ++r)
                Cs[(lq * 4 + r) * (64 * D) + (ni * 16 + lr) * D + w] =
                    acc[mc][ni][r] * PW;
        __syncthreads();
        constexpr int F4 = 16 * 16 * D;       // float4s in chunk
        for (int f = tid; f < F4; f += D * 64) {
            const int row = f / (16 * D);
            const int c4  = f % (16 * D);
            *(float4v*)(out + (size_t)(m0 + mc * 16 + row) * DTOT + XOFF + n0 * D + c4 * 4) =
                *(const float4v*)(Cs + f * 4);
        }
        __syncthreads();
    }
}

extern "C" void kernel_launch(void* const* d_in, const int* in_sizes, int n_in,
                              void* d_out, int out_size, void* d_ws, size_t ws_size,
                              hipStream_t stream) {
    const float* x  = (const float*)d_in[0];
    const float* w0 = (const float*)d_in[1];
    const float* w1 = (const float*)d_in[2];
    const float* w2 = (const float*)d_in[3];
    const float* b0 = (const float*)d_in[4];
    float* out = (float*)d_out;

    unsigned short* Xp = (unsigned short*)d_ws;
    unsigned short* Wt = (unsigned short*)((char*)d_ws + XPL_BYTES);

    deint_x<<<dim3(BATCH), dim3(256), 0, stream>>>(x, Xp);
    conv_w<<<dim3(192), dim3(256), 0, stream>>>(w0, w1, w2, Wt);
    gemm_d35<5, 4, 2048, 2><<<dim3(8, 64), dim3(320), 0, stream>>>(Xp, Wt, out);
    gemm_d35<3, 1, 512, 1><<<dim3(8, 64), dim3(192), 0, stream>>>(Xp, Wt, out);
    gemm_d1<<<dim3(4, 32), dim3(256), 0, stream>>>(Xp, Wt, b0, out);
}

// Round 6
// 192.807 us; speedup vs baseline: 1.0585x; 1.0585x over previous
//
#include <hip/hip_runtime.h>

// Round 6: two launches.
//  L1 prep (4288 blocks): rows 0..4095 deinterleave x -> Xp[9][4096][512] bf16;
//     blocks 4096.. convert W -> Wt[ch][n][k] bf16 transposed.
//  L2 gemm_all (1152 blocks, 320 thr): d5 (512 blks) -> d3 (512) -> d1 (128).
//     d35: 64x64xD-irrep tile, wave i = plane i, gld16 staging, LDS-interleave
//     epilogue (verified R5). d1: m97-style 128x128, 4 waves (+1 idle).

#define BATCH 4096
#define DTOT 4608
#define NMUL 512

typedef __attribute__((ext_vector_type(8))) short short8;
typedef __attribute__((ext_vector_type(8))) unsigned short ushort8;
typedef __attribute__((ext_vector_type(4))) float float4v;

#define XPL_BYTES (9ull * BATCH * NMUL * 2)

__device__ __forceinline__ unsigned short f2bf(float f) {
    unsigned int u = __builtin_bit_cast(unsigned int, f);
    return (unsigned short)((u + 0x7fffu + ((u >> 16) & 1u)) >> 16);
}
__device__ __forceinline__ void gld16(const unsigned short* g, unsigned short* l) {
    __builtin_amdgcn_global_load_lds(
        (const __attribute__((address_space(1))) unsigned int*)(const void*)g,
        (__attribute__((address_space(3))) unsigned int*)(void*)l, 16, 0, 0);
}
__device__ __forceinline__ void colmap(int col, int& c, int& u) {
    if (col < 512)       { c = 0; u = col; }
    else if (col < 2048) { int t = col - 512;  c = 1 + t % 3; u = t / 3; }
    else                 { int t = col - 2048; c = 4 + t % 5; u = t / 5; }
}

// ---- L1: prep (deint rows + W convert tiles) ----
__global__ __launch_bounds__(256) void prep(const float* __restrict__ x,
                                            const float* __restrict__ w0,
                                            const float* __restrict__ w1,
                                            const float* __restrict__ w2,
                                            unsigned short* __restrict__ Xp,
                                            unsigned short* __restrict__ Wt) {
    __shared__ unsigned short buf[4608];      // row buf (4608) == 64x72 tile
    const int tid = threadIdx.x;
    const int b = blockIdx.x;
    if (b < BATCH) {
        const int row = b;
        const float4v* src = (const float4v*)(x + (size_t)row * DTOT);
        for (int p = tid; p < DTOT / 4; p += 256) {
            float4v v = src[p];
#pragma unroll
            for (int j = 0; j < 4; ++j) {
                int c, u; colmap(p * 4 + j, c, u);
                buf[c * NMUL + u] = f2bf(v[j]);
            }
        }
        __syncthreads();
        for (int q = tid; q < DTOT / 8; q += 256) {
            const int c = q >> 6, u8 = q & 63;
            *(ushort8*)(Xp + ((size_t)(c * BATCH + row) * NMUL) + u8 * 8) =
                *(const ushort8*)&buf[c * NMUL + u8 * 8];
        }
    } else {
        const int t = b - BATCH;              // 0..191
        const int ch = t >> 6, tt = t & 63;
        const int tk = (tt >> 3) * 64, tn = (tt & 7) * 64;
        const float* W = (ch == 0) ? w0 : (ch == 1) ? w1 : w2;
        const int r0 = tid >> 4, c4 = (tid & 15) * 4;
#pragma unroll
        for (int rr = 0; rr < 4; ++rr) {
            const int row = r0 + rr * 16;     // k within tile
            float4v v = *(const float4v*)(W + (size_t)(tk + row) * NMUL + tn + c4);
#pragma unroll
            for (int j = 0; j < 4; ++j) buf[(c4 + j) * 72 + row] = f2bf(v[j]);
        }
        __syncthreads();
        for (int q = tid; q < 512; q += 256) {
            const int nn = q >> 3, k8 = q & 7;
            *(ushort8*)(Wt + ((size_t)(ch * NMUL + tn + nn) * NMUL) + tk + k8 * 8) =
                *(const ushort8*)&buf[nn * 72 + k8 * 8];
        }
    }
}

// ---- d in {3,5} body: 64 rows x 64 cols x D irreps, wave = plane ----
template <int D, int PBASE, int XOFF, int WCH>
__device__ __forceinline__ void body_d35(int rel,
                                         const unsigned short* __restrict__ Xp,
                                         const unsigned short* __restrict__ Wt,
                                         float* __restrict__ out,
                                         unsigned short* As, unsigned short* Bs) {
    float* Cs = (float*)As;

    const int tid = threadIdx.x;
    const int lane = tid & 63;
    const int w = tid >> 6;                   // 0..4; planes use 0..D-1
    const int lr = lane & 15;
    const int lq = lane >> 4;

    const int n0 = (rel & 7) * 64;
    const int m0 = (rel >> 3) * 64;

    const unsigned short* Ag =
        Xp + ((size_t)(PBASE + w) * BATCH + m0 + (lane >> 2)) * NMUL + (lane & 3) * 8;
    const unsigned short* Bg =
        Wt + ((size_t)WCH * NMUL + n0 + (lane >> 2)) * NMUL + (lane & 3) * 8;
    unsigned short* Al = As + w * 2048;

    float4v acc[4][4];
#pragma unroll
    for (int a = 0; a < 4; ++a)
#pragma unroll
        for (int b = 0; b < 4; ++b) acc[a][b] = (float4v)0.f;

    for (int kt = 0; kt < 16; ++kt) {
        const int ko = kt * 32;
        if (w < D) {
#pragma unroll
            for (int p = 0; p < 4; ++p)
                gld16(Ag + (size_t)p * 16 * NMUL + ko, Al + p * 512);
            for (int p = w; p < 4; p += D)
                gld16(Bg + (size_t)p * 16 * NMUL + ko, Bs + p * 512);
        }
        __syncthreads();
        if (w < D) {
            short8 af[4], bf[4];
#pragma unroll
            for (int mi = 0; mi < 4; ++mi)
                af[mi] = *(const short8*)(Al + (mi * 16 + lr) * 32 + lq * 8);
#pragma unroll
            for (int ni = 0; ni < 4; ++ni)
                bf[ni] = *(const short8*)(Bs + (ni * 16 + lr) * 32 + lq * 8);
#pragma unroll
            for (int mi = 0; mi < 4; ++mi)
#pragma unroll
                for (int ni = 0; ni < 4; ++ni)
                    acc[mi][ni] = __builtin_amdgcn_mfma_f32_16x16x32_bf16(
                        af[mi], bf[ni], acc[mi][ni], 0, 0, 0);
        }
        __syncthreads();
    }

    const float PW = 0.044194173824159216f;
#pragma unroll
    for (int mc = 0; mc < 4; ++mc) {
        if (w < D) {
#pragma unroll
            for (int ni = 0; ni < 4; ++ni)
#pragma unroll
                for (int r = 0; r < 4; ++r)
                    Cs[(lq * 4 + r) * (64 * D) + (ni * 16 + lr) * D + w] =
                        acc[mc][ni][r] * PW;
        }
        __syncthreads();
        constexpr int F4 = 16 * 16 * D;
        for (int f = tid; f < F4; f += 320) {
            const int row = f / (16 * D);
            const int c4  = f % (16 * D);
            *(float4v*)(out + (size_t)(m0 + mc * 16 + row) * DTOT + XOFF + n0 * D + c4 * 4) =
                *(const float4v*)(Cs + f * 4);
        }
        __syncthreads();
    }
}

// ---- d=1 body: m97-style 128x128, waves 0..3 (wave 4 barriers only) ----
__device__ __forceinline__ void body_d1(int rel,
                                        const unsigned short* __restrict__ Xp,
                                        const unsigned short* __restrict__ Wt,
                                        const float* __restrict__ b0,
                                        float* __restrict__ out,
                                        unsigned short* As, unsigned short* Bs) {
    const int tid = threadIdx.x;
    const int lane = tid & 63;
    const int w = tid >> 6;
    const int lr = lane & 15;
    const int lq = lane >> 4;
    const int wm = (w >> 1) * 64;
    const int wn = (w & 1) * 64;

    const int n0 = (rel & 3) * 128;
    const int m0 = (rel >> 2) * 128;

    const unsigned short* Ag = Xp + (size_t)(m0 + w * 32 + (lane >> 2)) * NMUL + (lane & 3) * 8;
    const unsigned short* Bg = Wt + (size_t)(n0 + w * 32 + (lane >> 2)) * NMUL + (lane & 3) * 8;
    unsigned short* Al = As + w * 1024;
    unsigned short* Bl = Bs + w * 1024;

    float4v acc[4][4];
#pragma unroll
    for (int a = 0; a < 4; ++a)
#pragma unroll
        for (int b = 0; b < 4; ++b) acc[a][b] = (float4v)0.f;

    for (int kt = 0; kt < 16; ++kt) {
        const int ko = kt * 32;
        if (w < 4) {
            gld16(Ag + ko, Al);
            gld16(Ag + ko + 16 * NMUL, Al + 512);
            gld16(Bg + ko, Bl);
            gld16(Bg + ko + 16 * NMUL, Bl + 512);
        }
        __syncthreads();
        if (w < 4) {
            short8 af[4], bf[4];
#pragma unroll
            for (int mi = 0; mi < 4; ++mi)
                af[mi] = *(const short8*)(As + (wm + mi * 16 + lr) * 32 + lq * 8);
#pragma unroll
            for (int ni = 0; ni < 4; ++ni)
                bf[ni] = *(const short8*)(Bs + (wn + ni * 16 + lr) * 32 + lq * 8);
#pragma unroll
            for (int mi = 0; mi < 4; ++mi)
#pragma unroll
                for (int ni = 0; ni < 4; ++ni)
                    acc[mi][ni] = __builtin_amdgcn_mfma_f32_16x16x32_bf16(
                        af[mi], bf[ni], acc[mi][ni], 0, 0, 0);
        }
        __syncthreads();
    }

    if (w < 4) {
        const float PW = 0.044194173824159216f;
#pragma unroll
        for (int ni = 0; ni < 4; ++ni) {
            const int col = n0 + wn + ni * 16 + lr;
            const float bias = b0[col];
#pragma unroll
            for (int mi = 0; mi < 4; ++mi)
#pragma unroll
                for (int r = 0; r < 4; ++r)
                    out[(size_t)(m0 + wm + mi * 16 + lq * 4 + r) * DTOT + col] =
                        acc[mi][ni][r] * PW + bias;
        }
    }
}

// ---- L2: all 9 channel-GEMMs in one launch ----
__global__ __launch_bounds__(320) void gemm_all(const unsigned short* __restrict__ Xp,
                                                const unsigned short* __restrict__ Wt,
                                                const float* __restrict__ b0,
                                                float* __restrict__ out) {
    __shared__ __align__(16) unsigned short As[10240];  // 20 KiB (d5 planes / d1 A / Cs)
    __shared__ __align__(16) unsigned short Bs[4096];   // 8 KiB (d35 B 4KB / d1 B 8KB)

    const int b = blockIdx.x;
    if (b < 512)       body_d35<5, 4, 2048, 2>(b, Xp, Wt, out, As, Bs);
    else if (b < 1024) body_d35<3, 1, 512, 1>(b - 512, Xp, Wt, out, As, Bs);
    else               body_d1(b - 1024, Xp, Wt, b0, out, As, Bs);
}

extern "C" void kernel_launch(void* const* d_in, const int* in_sizes, int n_in,
                              void* d_out, int out_size, void* d_ws, size_t ws_size,
                              hipStream_t stream) {
    const float* x  = (const float*)d_in[0];
    const float* w0 = (const float*)d_in[1];
    const float* w1 = (const float*)d_in[2];
    const float* w2 = (const float*)d_in[3];
    const float* b0 = (const float*)d_in[4];
    float* out = (float*)d_out;

    unsigned short* Xp = (unsigned short*)d_ws;
    unsigned short* Wt = (unsigned short*)((char*)d_ws + XPL_BYTES);

    prep<<<dim3(BATCH + 192), dim3(256), 0, stream>>>(x, w0, w1, w2, Xp, Wt);
    gemm_all<<<dim3(1152), dim3(320), 0, stream>>>(Xp, Wt, b0, out);
}